// Round 1
// baseline (426.391 us; speedup 1.0000x reference)
//
#include <hip/hip_runtime.h>
#include <hip/hip_bf16.h>
#include <stdint.h>

typedef __bf16 bf16x8 __attribute__((ext_vector_type(8)));
typedef float f32x4 __attribute__((ext_vector_type(4)));

constexpr int S = 1024, Bsz = 16, Hd = 1024;
constexpr int M = S * Bsz;   // 16384
constexpr int N = 3 * Hd;    // 3072
constexpr int K = 1024;
constexpr int BM = 128, BN = 128, BK = 32;

__device__ __forceinline__ float fast_sigmoid(float x) { return 1.0f / (1.0f + __expf(-x)); }
__device__ __forceinline__ float fast_tanh(float x) { return 2.0f / (1.0f + __expf(-2.0f * x)) - 1.0f; }

// ---- fp32 -> bf16 conversion, 8 elems/thread ----
__global__ void convert_f32_bf16(const float* __restrict__ src, __bf16* __restrict__ dst, int n8) {
  int i = blockIdx.x * blockDim.x + threadIdx.x;
  if (i >= n8) return;
  const float4* s4 = (const float4*)src;
  float4 a = s4[2 * i], b = s4[2 * i + 1];
  bf16x8 v;
  v[0] = (__bf16)a.x; v[1] = (__bf16)a.y; v[2] = (__bf16)a.z; v[3] = (__bf16)a.w;
  v[4] = (__bf16)b.x; v[5] = (__bf16)b.y; v[6] = (__bf16)b.z; v[7] = (__bf16)b.w;
  *((bf16x8*)dst + i) = v;
}

// ---- bf16 MFMA GEMM (NT: C[m,n] = sum_k A[m,k]*W[n,k]) + bias + activation ----
// 128x128 tile, BK=32, 256 threads (4 waves, 2x2 of 64x64), 16x16x32 MFMA.
template <typename T>
__global__ __launch_bounds__(256) void gemm_act(const __bf16* __restrict__ A,
                                                const __bf16* __restrict__ Bw,
                                                const float* __restrict__ bias,
                                                T* __restrict__ Y) {
  __shared__ __align__(16) __bf16 As[BM][BK];  // 8 KB
  __shared__ __align__(16) __bf16 Bs[BN][BK];  // 8 KB
  const int t = threadIdx.x;
  const int lane = t & 63;
  const int wave = t >> 6;
  const int wm = wave >> 1, wn = wave & 1;
  const int tn = blockIdx.x % (N / BN);
  const int tm = blockIdx.x / (N / BN);
  const int m0 = tm * BM, n0 = tn * BN;
  const int lrow = lane & 15;
  const int quad = lane >> 4;

  f32x4 acc[4][4] = {};

  for (int k0 = 0; k0 < K; k0 += BK) {
    __syncthreads();
    // stage 128x32 bf16 A-tile and B-tile: 512 chunks of 16B each
#pragma unroll
    for (int i = 0; i < 2; ++i) {
      int c = t + i * 256;
      int row = c >> 2, cw = c & 3;
      *(uint4*)(&As[row][cw * 8]) = *(const uint4*)(A + (size_t)(m0 + row) * K + k0 + cw * 8);
      *(uint4*)(&Bs[row][cw * 8]) = *(const uint4*)(Bw + (size_t)(n0 + row) * K + k0 + cw * 8);
    }
    __syncthreads();
    // fragments: A[m=lane&15][k=quad*8+j], B[n=lane&15][k=quad*8+j]
    bf16x8 af[4], bfr[4];
#pragma unroll
    for (int mi = 0; mi < 4; ++mi)
      af[mi] = *(const bf16x8*)(&As[wm * 64 + mi * 16 + lrow][quad * 8]);
#pragma unroll
    for (int ni = 0; ni < 4; ++ni)
      bfr[ni] = *(const bf16x8*)(&Bs[wn * 64 + ni * 16 + lrow][quad * 8]);
#pragma unroll
    for (int mi = 0; mi < 4; ++mi)
#pragma unroll
      for (int ni = 0; ni < 4; ++ni)
        acc[mi][ni] = __builtin_amdgcn_mfma_f32_16x16x32_bf16(af[mi], bfr[ni], acc[mi][ni], 0, 0, 0);
  }

  // epilogue: C/D layout col=lane&15, row=quad*4+reg (m89/m91-verified)
#pragma unroll
  for (int ni = 0; ni < 4; ++ni) {
    int col = n0 + wn * 64 + ni * 16 + lrow;
    float bv = bias[col];
    bool is_tanh = (col < Hd);
#pragma unroll
    for (int mi = 0; mi < 4; ++mi) {
#pragma unroll
      for (int r = 0; r < 4; ++r) {
        int m = m0 + wm * 64 + mi * 16 + quad * 4 + r;
        float y = acc[mi][ni][r] + bv;
        float v = is_tanh ? fast_tanh(y) : fast_sigmoid(y);
        Y[(size_t)m * N + col] = (T)v;
      }
    }
  }
}

// ---- sequential scan over S; one thread per (b,h); batch-8 prefetch ----
template <typename T>
__global__ __launch_bounds__(64) void qrnn_scan(const T* __restrict__ Y,
                                                float* __restrict__ hout,
                                                float* __restrict__ clast) {
  int tid = blockIdx.x * blockDim.x + threadIdx.x;  // 0..16383
  int b = tid >> 10, h = tid & 1023;
  const size_t sstep = (size_t)Bsz * N;  // 49152
  size_t zoff = (size_t)b * N + h;
  size_t ooff = (size_t)b * Hd + h;
  float hp = 0.0f;
  for (int s0 = 0; s0 < S; s0 += 8) {
    float z[8], f[8], o[8];
#pragma unroll
    for (int j = 0; j < 8; ++j) {
      size_t base = zoff + (size_t)(s0 + j) * sstep;
      z[j] = (float)Y[base];
      f[j] = (float)Y[base + Hd];
      o[j] = (float)Y[base + 2 * Hd];
    }
#pragma unroll
    for (int j = 0; j < 8; ++j) {
      hp = f[j] * z[j] + (1.0f - f[j]) * hp;
      hout[ooff + (size_t)(s0 + j) * (Bsz * Hd)] = o[j] * hp;
    }
  }
  clast[tid] = hp;
}

extern "C" void kernel_launch(void* const* d_in, const int* in_sizes, int n_in,
                              void* d_out, int out_size, void* d_ws, size_t ws_size,
                              hipStream_t stream) {
  const float* X = (const float*)d_in[0];   // [1024,16,1024]
  const float* W = (const float*)d_in[1];   // [3072,1024]
  const float* bias = (const float*)d_in[2];// [3072]
  float* out = (float*)d_out;               // Hout (16777216) + C_last (16384)

  char* ws = (char*)d_ws;
  __bf16* Xb = (__bf16*)ws;                       // 33,554,432 B
  __bf16* Wb = (__bf16*)(ws + 33554432);          // 6,291,456 B
  void* Yv = (void*)(ws + 33554432 + 6291456);    // Y scratch

  const size_t need_f32 = 39845888ull + (size_t)M * N * 4ull;  // ~230 MB
  bool yf32 = (ws_size >= need_f32);

  // conversions: X has 2,097,152 groups of 8; W has 393,216
  convert_f32_bf16<<<8192, 256, 0, stream>>>(X, Xb, 2097152);
  convert_f32_bf16<<<1536, 256, 0, stream>>>(W, Wb, 393216);

  dim3 ggrid((M / BM) * (N / BN));  // 128*24 = 3072
  if (yf32) {
    gemm_act<float><<<ggrid, 256, 0, stream>>>(Xb, Wb, bias, (float*)Yv);
    qrnn_scan<float><<<256, 64, 0, stream>>>((const float*)Yv, out, out + 16777216);
  } else {
    gemm_act<__bf16><<<ggrid, 256, 0, stream>>>(Xb, Wb, bias, (__bf16*)Yv);
    qrnn_scan<__bf16><<<256, 64, 0, stream>>>((const __bf16*)Yv, out, out + 16777216);
  }
}

// Round 2
// 374.196 us; speedup vs baseline: 1.1395x; 1.1395x over previous
//
#include <hip/hip_runtime.h>
#include <hip/hip_bf16.h>
#include <stdint.h>

typedef __bf16 bf16x8 __attribute__((ext_vector_type(8)));
typedef float f32x4 __attribute__((ext_vector_type(4)));

constexpr int S = 1024, Bsz = 16, Hd = 1024;
constexpr int M = S * Bsz;   // 16384
constexpr int N = 3 * Hd;    // 3072
constexpr int K = 1024;
constexpr int BM = 128, BN = 128, BK = 32;

__device__ __forceinline__ float fast_sigmoid(float x) { return 1.0f / (1.0f + __expf(-x)); }
__device__ __forceinline__ float fast_tanh(float x) { return 2.0f / (1.0f + __expf(-2.0f * x)) - 1.0f; }

// async global->LDS 16B per lane; LDS dest is wave-uniform base + lane*16
__device__ __forceinline__ void gld_lds16(const __bf16* g, __bf16* l) {
  __builtin_amdgcn_global_load_lds(
      (const __attribute__((address_space(1))) void*)g,
      (__attribute__((address_space(3))) void*)l,
      16, 0, 0);
}

// ---- fp32 -> bf16 conversion, 8 elems/thread ----
__global__ void convert_f32_bf16(const float* __restrict__ src, __bf16* __restrict__ dst, int n8) {
  int i = blockIdx.x * blockDim.x + threadIdx.x;
  if (i >= n8) return;
  const float4* s4 = (const float4*)src;
  float4 a = s4[2 * i], b = s4[2 * i + 1];
  bf16x8 v;
  v[0] = (__bf16)a.x; v[1] = (__bf16)a.y; v[2] = (__bf16)a.z; v[3] = (__bf16)a.w;
  v[4] = (__bf16)b.x; v[5] = (__bf16)b.y; v[6] = (__bf16)b.z; v[7] = (__bf16)b.w;
  *((bf16x8*)dst + i) = v;
}

// ---- bf16 MFMA GEMM (NT: C[m,n] = sum_k A[m,k]*W[n,k]) + bias + activation ----
// 128x128 tile, BK=32, 256 threads (4 waves, 2x2 of 64x64), 16x16x32 MFMA.
// Staging via global_load_lds width=16: chunk c=t (it=0) / t+256 (it=1),
// LDS bytes c*16 == As[row=c>>2][col8=c&3] -> lane-contiguous, layout unchanged.
template <typename T>
__global__ __launch_bounds__(256) void gemm_act(const __bf16* __restrict__ A,
                                                const __bf16* __restrict__ Bw,
                                                const float* __restrict__ bias,
                                                T* __restrict__ Y) {
  __shared__ __align__(16) __bf16 As[BM * BK];  // 8 KB, flat: elem = row*32 + col
  __shared__ __align__(16) __bf16 Bs[BN * BK];  // 8 KB
  const int t = threadIdx.x;
  const int lane = t & 63;
  const int wave = t >> 6;
  const int wm = wave >> 1, wn = wave & 1;
  const int tn = blockIdx.x % (N / BN);
  const int tm = blockIdx.x / (N / BN);
  const int m0 = tm * BM, n0 = tn * BN;
  const int lrow = lane & 15;
  const int quad = lane >> 4;

  // per-lane global staging addresses (chunk c = t and c = t + 256)
  const int srow = t >> 2;      // 0..63
  const int scw = t & 3;        // 16B sub-chunk within 32-elem row
  const __bf16* gA0 = A + (size_t)(m0 + srow) * K + scw * 8;
  const __bf16* gA1 = gA0 + (size_t)64 * K;
  const __bf16* gB0 = Bw + (size_t)(n0 + srow) * K + scw * 8;
  const __bf16* gB1 = gB0 + (size_t)64 * K;
  // wave-uniform LDS bases (elements): it*2048 + wave*512
  __bf16* lA0 = As + wave * 512;
  __bf16* lA1 = As + 2048 + wave * 512;
  __bf16* lB0 = Bs + wave * 512;
  __bf16* lB1 = Bs + 2048 + wave * 512;

  f32x4 acc[4][4] = {};

  for (int k0 = 0; k0 < K; k0 += BK) {
    __syncthreads();
    gld_lds16(gA0, lA0);
    gld_lds16(gA1, lA1);
    gld_lds16(gB0, lB0);
    gld_lds16(gB1, lB1);
    gA0 += BK; gA1 += BK; gB0 += BK; gB1 += BK;
    __syncthreads();  // compiler emits s_waitcnt vmcnt(0) before s_barrier

    // fragments: A[m=lane&15][k=quad*8+j], B[n=lane&15][k=quad*8+j]
    bf16x8 af[4], bfr[4];
#pragma unroll
    for (int mi = 0; mi < 4; ++mi)
      af[mi] = *(const bf16x8*)(&As[(wm * 64 + mi * 16 + lrow) * BK + quad * 8]);
#pragma unroll
    for (int ni = 0; ni < 4; ++ni)
      bfr[ni] = *(const bf16x8*)(&Bs[(wn * 64 + ni * 16 + lrow) * BK + quad * 8]);
#pragma unroll
    for (int mi = 0; mi < 4; ++mi)
#pragma unroll
      for (int ni = 0; ni < 4; ++ni)
        acc[mi][ni] = __builtin_amdgcn_mfma_f32_16x16x32_bf16(af[mi], bfr[ni], acc[mi][ni], 0, 0, 0);
  }

  // epilogue: C/D layout col=lane&15, row=quad*4+reg (m89/m91-verified)
#pragma unroll
  for (int ni = 0; ni < 4; ++ni) {
    int col = n0 + wn * 64 + ni * 16 + lrow;
    float bv = bias[col];
    bool is_tanh = (col < Hd);
#pragma unroll
    for (int mi = 0; mi < 4; ++mi) {
#pragma unroll
      for (int r = 0; r < 4; ++r) {
        int m = m0 + wm * 64 + mi * 16 + quad * 4 + r;
        float y = acc[mi][ni][r] + bv;
        float v = is_tanh ? fast_tanh(y) : fast_sigmoid(y);
        Y[(size_t)m * N + col] = (T)v;
      }
    }
  }
}

// ---- sequential scan over S; one thread per (b,h); batch-16 prefetch ----
// Latency-bound at 1 wave/CU: time ~ chunk_count * HBM latency, so deepen
// the prefetch (48 loads in flight < vmcnt max 63).
template <typename T>
__global__ __launch_bounds__(64) void qrnn_scan(const T* __restrict__ Y,
                                                float* __restrict__ hout,
                                                float* __restrict__ clast) {
  int tid = blockIdx.x * blockDim.x + threadIdx.x;  // 0..16383
  int b = tid >> 10, h = tid & 1023;
  const size_t sstep = (size_t)Bsz * N;  // 49152
  size_t zoff = (size_t)b * N + h;
  size_t ooff = (size_t)b * Hd + h;
  float hp = 0.0f;
  constexpr int DEPTH = 16;
  for (int s0 = 0; s0 < S; s0 += DEPTH) {
    float z[DEPTH], f[DEPTH], o[DEPTH];
#pragma unroll
    for (int j = 0; j < DEPTH; ++j) {
      size_t base = zoff + (size_t)(s0 + j) * sstep;
      z[j] = (float)Y[base];
      f[j] = (float)Y[base + Hd];
      o[j] = (float)Y[base + 2 * Hd];
    }
#pragma unroll
    for (int j = 0; j < DEPTH; ++j) {
      hp = f[j] * z[j] + (1.0f - f[j]) * hp;
      hout[ooff + (size_t)(s0 + j) * (Bsz * Hd)] = o[j] * hp;
    }
  }
  clast[tid] = hp;
}

extern "C" void kernel_launch(void* const* d_in, const int* in_sizes, int n_in,
                              void* d_out, int out_size, void* d_ws, size_t ws_size,
                              hipStream_t stream) {
  const float* X = (const float*)d_in[0];   // [1024,16,1024]
  const float* W = (const float*)d_in[1];   // [3072,1024]
  const float* bias = (const float*)d_in[2];// [3072]
  float* out = (float*)d_out;               // Hout (16777216) + C_last (16384)

  char* ws = (char*)d_ws;
  __bf16* Xb = (__bf16*)ws;                       // 33,554,432 B
  __bf16* Wb = (__bf16*)(ws + 33554432);          // 6,291,456 B
  void* Yv = (void*)(ws + 33554432 + 6291456);    // Y scratch

  const size_t need_f32 = 39845888ull + (size_t)M * N * 4ull;  // ~230 MB
  bool yf32 = (ws_size >= need_f32);

  // conversions: X has 2,097,152 groups of 8; W has 393,216
  convert_f32_bf16<<<8192, 256, 0, stream>>>(X, Xb, 2097152);
  convert_f32_bf16<<<1536, 256, 0, stream>>>(W, Wb, 393216);

  dim3 ggrid((M / BM) * (N / BN));  // 128*24 = 3072
  if (yf32) {
    gemm_act<float><<<ggrid, 256, 0, stream>>>(Xb, Wb, bias, (float*)Yv);
    qrnn_scan<float><<<256, 64, 0, stream>>>((const float*)Yv, out, out + 16777216);
  } else {
    gemm_act<__bf16><<<ggrid, 256, 0, stream>>>(Xb, Wb, bias, (__bf16*)Yv);
    qrnn_scan<__bf16><<<256, 64, 0, stream>>>((const __bf16*)Yv, out, out + 16777216);
  }
}

// Round 3
// 335.362 us; speedup vs baseline: 1.2714x; 1.1158x over previous
//
#include <hip/hip_runtime.h>
#include <hip/hip_bf16.h>
#include <stdint.h>

typedef __bf16 bf16x8 __attribute__((ext_vector_type(8)));
typedef float f32x4 __attribute__((ext_vector_type(4)));

constexpr int S = 1024, Bsz = 16, Hd = 1024;
constexpr int M = S * Bsz;   // 16384
constexpr int N = 3 * Hd;    // 3072
constexpr int K = 1024;
constexpr int BM = 128, BN = 128, BK = 32;
constexpr int NCH = 32, CS = S / NCH;  // 32 chunks x 32 steps
constexpr int BH = Bsz * Hd;           // 16384

__device__ __forceinline__ float fast_sigmoid(float x) { return 1.0f / (1.0f + __expf(-x)); }
__device__ __forceinline__ float fast_tanh(float x) { return 2.0f / (1.0f + __expf(-2.0f * x)) - 1.0f; }

// async global->LDS 16B per lane; LDS dest is wave-uniform base + lane*16
__device__ __forceinline__ void gld_lds16(const __bf16* g, __bf16* l) {
  __builtin_amdgcn_global_load_lds(
      (const __attribute__((address_space(1))) void*)g,
      (__attribute__((address_space(3))) void*)l,
      16, 0, 0);
}

// ---- fp32 -> bf16 conversion, 8 elems/thread ----
__global__ void convert_f32_bf16(const float* __restrict__ src, __bf16* __restrict__ dst, int n8) {
  int i = blockIdx.x * blockDim.x + threadIdx.x;
  if (i >= n8) return;
  const float4* s4 = (const float4*)src;
  float4 a = s4[2 * i], b = s4[2 * i + 1];
  bf16x8 v;
  v[0] = (__bf16)a.x; v[1] = (__bf16)a.y; v[2] = (__bf16)a.z; v[3] = (__bf16)a.w;
  v[4] = (__bf16)b.x; v[5] = (__bf16)b.y; v[6] = (__bf16)b.z; v[7] = (__bf16)b.w;
  *((bf16x8*)dst + i) = v;
}

// ---- bf16 MFMA GEMM (NT) + bias + activation, XOR-swizzled LDS ----
// Logical (row, cw) stored at slot cw_store = cw ^ swz(row), swz(r)=(r^(r>>2))&3.
// global_load_lds writes stay lane-contiguous (slot order); the *global* source
// is permuted per lane (still within one 64B row segment -> coalesced).
// Read fragment (row r, quad q) at slot q ^ swz(r): banks 2-way aliased = free.
template <typename T>
__global__ __launch_bounds__(256) void gemm_act(const __bf16* __restrict__ A,
                                                const __bf16* __restrict__ Bw,
                                                const float* __restrict__ bias,
                                                T* __restrict__ Y) {
  __shared__ __align__(16) __bf16 As[BM * BK];  // 8 KB flat, slot c at bytes c*16
  __shared__ __align__(16) __bf16 Bs[BN * BK];  // 8 KB
  const int t = threadIdx.x;
  const int lane = t & 63;
  const int wave = t >> 6;
  const int wm = wave >> 1, wn = wave & 1;
  const int tn = blockIdx.x % (N / BN);
  const int tm = blockIdx.x / (N / BN);
  const int m0 = tm * BM, n0 = tn * BN;
  const int lrow = lane & 15;
  const int quad = lane >> 4;

  // staging: chunk c = t (rows 0..63) and c = t+256 (rows 64..127)
  const int srow = t >> 2;                       // 0..63
  const int cw_store = t & 3;
  const int sswz = (srow ^ (srow >> 2)) & 3;     // swz(srow) == swz(srow+64)
  const int cw_log = cw_store ^ sswz;
  const __bf16* gA0 = A + (size_t)(m0 + srow) * K + cw_log * 8;
  const __bf16* gA1 = A + (size_t)(m0 + srow + 64) * K + cw_log * 8;
  const __bf16* gB0 = Bw + (size_t)(n0 + srow) * K + cw_log * 8;
  const __bf16* gB1 = Bw + (size_t)(n0 + srow + 64) * K + cw_log * 8;
  __bf16* lA0 = As + wave * 512;
  __bf16* lA1 = As + 2048 + wave * 512;
  __bf16* lB0 = Bs + wave * 512;
  __bf16* lB1 = Bs + 2048 + wave * 512;

  const int rswz = (lrow ^ (lrow >> 2)) & 3;     // swz of fragment row (r&15==lrow)

  f32x4 acc[4][4] = {};

  for (int k0 = 0; k0 < K; k0 += BK) {
    __syncthreads();
    gld_lds16(gA0, lA0);
    gld_lds16(gA1, lA1);
    gld_lds16(gB0, lB0);
    gld_lds16(gB1, lB1);
    gA0 += BK; gA1 += BK; gB0 += BK; gB1 += BK;
    __syncthreads();

    bf16x8 af[4], bfr[4];
#pragma unroll
    for (int mi = 0; mi < 4; ++mi)
      af[mi] = *(const bf16x8*)(&As[(wm * 64 + mi * 16 + lrow) * BK + ((quad ^ rswz) * 8)]);
#pragma unroll
    for (int ni = 0; ni < 4; ++ni)
      bfr[ni] = *(const bf16x8*)(&Bs[(wn * 64 + ni * 16 + lrow) * BK + ((quad ^ rswz) * 8)]);
#pragma unroll
    for (int mi = 0; mi < 4; ++mi)
#pragma unroll
      for (int ni = 0; ni < 4; ++ni)
        acc[mi][ni] = __builtin_amdgcn_mfma_f32_16x16x32_bf16(af[mi], bfr[ni], acc[mi][ni], 0, 0, 0);
  }

  // epilogue: C/D layout col=lane&15, row=quad*4+reg (m89/m91-verified)
#pragma unroll
  for (int ni = 0; ni < 4; ++ni) {
    int col = n0 + wn * 64 + ni * 16 + lrow;
    float bv = bias[col];
    bool is_tanh = (col < Hd);
#pragma unroll
    for (int mi = 0; mi < 4; ++mi) {
#pragma unroll
      for (int r = 0; r < 4; ++r) {
        int m = m0 + wm * 64 + mi * 16 + quad * 4 + r;
        float y = acc[mi][ni][r] + bv;
        float v = is_tanh ? fast_tanh(y) : fast_sigmoid(y);
        Y[(size_t)m * N + col] = (T)v;
      }
    }
  }
}

// ---- chunked affine scan: h_t = f*z + (1-f)*h == a*h + b, a=1-f, b=f*z ----
// pass1: per-chunk composition (A,B): h_out = A*h_in + B
template <typename T>
__global__ __launch_bounds__(256) void scan_pass1(const T* __restrict__ Y,
                                                  float* __restrict__ Ac,
                                                  float* __restrict__ Bc) {
  int tid = blockIdx.x * 256 + threadIdx.x;  // 0 .. NCH*BH-1
  int c = tid >> 14;
  int bh = tid & (BH - 1);
  int b = bh >> 10, h = bh & (Hd - 1);
  const size_t sstep = (size_t)Bsz * N;
  size_t base0 = (size_t)b * N + h + (size_t)(c * CS) * sstep;
  float A = 1.0f, B = 0.0f;
  for (int j0 = 0; j0 < CS; j0 += 8) {
    float z[8], f[8];
#pragma unroll
    for (int j = 0; j < 8; ++j) {
      size_t base = base0 + (size_t)(j0 + j) * sstep;
      z[j] = (float)Y[base];
      f[j] = (float)Y[base + Hd];
    }
#pragma unroll
    for (int j = 0; j < 8; ++j) {
      float a = 1.0f - f[j];
      B = fmaf(a, B, f[j] * z[j]);
      A *= a;
    }
  }
  Ac[tid] = A;
  Bc[tid] = B;
}

// pass2: chain chunk states; emit per-chunk h_in and C_last
__global__ __launch_bounds__(256) void scan_pass2(const float* __restrict__ Ac,
                                                  const float* __restrict__ Bc,
                                                  float* __restrict__ hin,
                                                  float* __restrict__ clast) {
  int bh = blockIdx.x * 256 + threadIdx.x;  // 0..BH-1
  float h = 0.0f;
#pragma unroll 4
  for (int c = 0; c < NCH; ++c) {
    hin[c * BH + bh] = h;
    h = fmaf(Ac[c * BH + bh], h, Bc[c * BH + bh]);
  }
  clast[bh] = h;
}

// pass3: replay chunk from known h_in, write Hout = o * h
template <typename T>
__global__ __launch_bounds__(256) void scan_pass3(const T* __restrict__ Y,
                                                  const float* __restrict__ hin,
                                                  float* __restrict__ hout) {
  int tid = blockIdx.x * 256 + threadIdx.x;
  int c = tid >> 14;
  int bh = tid & (BH - 1);
  int b = bh >> 10, h = bh & (Hd - 1);
  const size_t sstep = (size_t)Bsz * N;
  size_t base0 = (size_t)b * N + h + (size_t)(c * CS) * sstep;
  size_t obase = (size_t)b * Hd + h + (size_t)(c * CS) * BH;
  float hp = hin[tid];
  for (int j0 = 0; j0 < CS; j0 += 8) {
    float z[8], f[8], o[8];
#pragma unroll
    for (int j = 0; j < 8; ++j) {
      size_t base = base0 + (size_t)(j0 + j) * sstep;
      z[j] = (float)Y[base];
      f[j] = (float)Y[base + Hd];
      o[j] = (float)Y[base + 2 * Hd];
    }
#pragma unroll
    for (int j = 0; j < 8; ++j) {
      hp = fmaf(f[j], z[j] - hp, hp);  // f*z + (1-f)*h
      hout[obase + (size_t)(j0 + j) * BH] = o[j] * hp;
    }
  }
}

extern "C" void kernel_launch(void* const* d_in, const int* in_sizes, int n_in,
                              void* d_out, int out_size, void* d_ws, size_t ws_size,
                              hipStream_t stream) {
  const float* X = (const float*)d_in[0];    // [1024,16,1024]
  const float* W = (const float*)d_in[1];    // [3072,1024]
  const float* bias = (const float*)d_in[2]; // [3072]
  float* out = (float*)d_out;                // Hout (16777216) + C_last (16384)

  char* ws = (char*)d_ws;
  __bf16* Xb = (__bf16*)ws;                      // 33,554,432 B
  __bf16* Wb = (__bf16*)(ws + 33554432);         // 6,291,456 B
  char* Yp = ws + 39845888;

  const size_t y_f32 = (size_t)M * N * 4ull;     // 201,326,592
  const size_t y_bf16 = (size_t)M * N * 2ull;    // 100,663,296
  const size_t scratch = 3ull * NCH * BH * 4ull; // 6,291,456
  bool yf32 = (ws_size >= 39845888ull + y_f32 + scratch);

  size_t ybytes = yf32 ? y_f32 : y_bf16;
  float* Ac = (float*)(Yp + ybytes);
  float* Bc = Ac + NCH * BH;
  float* hin = Bc + NCH * BH;

  convert_f32_bf16<<<8192, 256, 0, stream>>>(X, Xb, 2097152);
  convert_f32_bf16<<<1536, 256, 0, stream>>>(W, Wb, 393216);

  dim3 ggrid((M / BM) * (N / BN));  // 3072
  dim3 sgrid(NCH * BH / 256);       // 2048
  if (yf32) {
    float* Yv = (float*)Yp;
    gemm_act<float><<<ggrid, 256, 0, stream>>>(Xb, Wb, bias, Yv);
    scan_pass1<float><<<sgrid, 256, 0, stream>>>(Yv, Ac, Bc);
    scan_pass2<<<BH / 256, 256, 0, stream>>>(Ac, Bc, hin, out + 16777216);
    scan_pass3<float><<<sgrid, 256, 0, stream>>>(Yv, hin, out);
  } else {
    __bf16* Yv = (__bf16*)Yp;
    gemm_act<__bf16><<<ggrid, 256, 0, stream>>>(Xb, Wb, bias, Yv);
    scan_pass1<__bf16><<<sgrid, 256, 0, stream>>>(Yv, Ac, Bc);
    scan_pass2<<<BH / 256, 256, 0, stream>>>(Ac, Bc, hin, out + 16777216);
    scan_pass3<__bf16><<<sgrid, 256, 0, stream>>>(Yv, hin, out);
  }
}

// Round 4
// 308.860 us; speedup vs baseline: 1.3805x; 1.0858x over previous
//
#include <hip/hip_runtime.h>
#include <hip/hip_bf16.h>
#include <stdint.h>

typedef __bf16 bf16x8 __attribute__((ext_vector_type(8)));
typedef float f32x4 __attribute__((ext_vector_type(4)));

constexpr int S = 1024, Bsz = 16, Hd = 1024;
constexpr int M = S * Bsz;   // 16384
constexpr int N = 3 * Hd;    // 3072
constexpr int K = 1024;
constexpr int BM = 128, BN = 128, BK = 32;
constexpr int NCH = 32, CS = S / NCH;  // 32 chunks x 32 steps
constexpr int BH = Bsz * Hd;           // 16384

__device__ __forceinline__ float fast_sigmoid(float x) { return 1.0f / (1.0f + __expf(-x)); }
__device__ __forceinline__ float fast_tanh(float x) { return 2.0f / (1.0f + __expf(-2.0f * x)) - 1.0f; }

// async global->LDS 16B per lane; LDS dest is wave-uniform base + lane*16
__device__ __forceinline__ void gld_lds16(const __bf16* g, __bf16* l) {
  __builtin_amdgcn_global_load_lds(
      (const __attribute__((address_space(1))) void*)g,
      (__attribute__((address_space(3))) void*)l,
      16, 0, 0);
}

// ---- fp32 -> bf16 conversion, 8 elems/thread ----
__global__ void convert_f32_bf16(const float* __restrict__ src, __bf16* __restrict__ dst, int n8) {
  int i = blockIdx.x * blockDim.x + threadIdx.x;
  if (i >= n8) return;
  const float4* s4 = (const float4*)src;
  float4 a = s4[2 * i], b = s4[2 * i + 1];
  bf16x8 v;
  v[0] = (__bf16)a.x; v[1] = (__bf16)a.y; v[2] = (__bf16)a.z; v[3] = (__bf16)a.w;
  v[4] = (__bf16)b.x; v[5] = (__bf16)b.y; v[6] = (__bf16)b.z; v[7] = (__bf16)b.w;
  *((bf16x8*)dst + i) = v;
}

// ---- bf16 MFMA GEMM (NT: C[m,n] = sum_k A[m,k]*W[n,k]) + bias + activation ----
// 128x128 tile, BK=32, 256 threads (4 waves, 2x2 of 64x64), 16x16x32 MFMA.
// Plain (unswizzled) layout: SQ_LDS_BANK_CONFLICT is structural to wave64
// ds_read_b128 (4 cyc/inst, invariant under swizzle — measured R1/R2/R3).
__global__ __launch_bounds__(256) void gemm_act(const __bf16* __restrict__ A,
                                                const __bf16* __restrict__ Bw,
                                                const float* __restrict__ bias,
                                                __bf16* __restrict__ Y) {
  __shared__ __align__(16) __bf16 As[BM * BK];  // 8 KB, flat: elem = row*32 + col
  __shared__ __align__(16) __bf16 Bs[BN * BK];  // 8 KB
  const int t = threadIdx.x;
  const int lane = t & 63;
  const int wave = t >> 6;
  const int wm = wave >> 1, wn = wave & 1;
  const int tn = blockIdx.x % (N / BN);
  const int tm = blockIdx.x / (N / BN);
  const int m0 = tm * BM, n0 = tn * BN;
  const int lrow = lane & 15;
  const int quad = lane >> 4;

  // per-lane global staging addresses (chunk c = t and c = t + 256)
  const int srow = t >> 2;      // 0..63
  const int scw = t & 3;        // 16B sub-chunk within 32-elem row
  const __bf16* gA0 = A + (size_t)(m0 + srow) * K + scw * 8;
  const __bf16* gA1 = gA0 + (size_t)64 * K;
  const __bf16* gB0 = Bw + (size_t)(n0 + srow) * K + scw * 8;
  const __bf16* gB1 = gB0 + (size_t)64 * K;
  // wave-uniform LDS bases (elements): it*2048 + wave*512
  __bf16* lA0 = As + wave * 512;
  __bf16* lA1 = As + 2048 + wave * 512;
  __bf16* lB0 = Bs + wave * 512;
  __bf16* lB1 = Bs + 2048 + wave * 512;

  f32x4 acc[4][4] = {};

  for (int k0 = 0; k0 < K; k0 += BK) {
    __syncthreads();
    gld_lds16(gA0, lA0);
    gld_lds16(gA1, lA1);
    gld_lds16(gB0, lB0);
    gld_lds16(gB1, lB1);
    gA0 += BK; gA1 += BK; gB0 += BK; gB1 += BK;
    __syncthreads();

    // fragments: A[m=lane&15][k=quad*8+j], B[n=lane&15][k=quad*8+j]
    bf16x8 af[4], bfr[4];
#pragma unroll
    for (int mi = 0; mi < 4; ++mi)
      af[mi] = *(const bf16x8*)(&As[(wm * 64 + mi * 16 + lrow) * BK + quad * 8]);
#pragma unroll
    for (int ni = 0; ni < 4; ++ni)
      bfr[ni] = *(const bf16x8*)(&Bs[(wn * 64 + ni * 16 + lrow) * BK + quad * 8]);
#pragma unroll
    for (int mi = 0; mi < 4; ++mi)
#pragma unroll
      for (int ni = 0; ni < 4; ++ni)
        acc[mi][ni] = __builtin_amdgcn_mfma_f32_16x16x32_bf16(af[mi], bfr[ni], acc[mi][ni], 0, 0, 0);
  }

  // epilogue: C/D layout col=lane&15, row=quad*4+reg (m89/m91-verified)
#pragma unroll
  for (int ni = 0; ni < 4; ++ni) {
    int col = n0 + wn * 64 + ni * 16 + lrow;
    float bv = bias[col];
    bool is_tanh = (col < Hd);
#pragma unroll
    for (int mi = 0; mi < 4; ++mi) {
#pragma unroll
      for (int r = 0; r < 4; ++r) {
        int m = m0 + wm * 64 + mi * 16 + quad * 4 + r;
        float y = acc[mi][ni][r] + bv;
        float v = is_tanh ? fast_tanh(y) : fast_sigmoid(y);
        Y[(size_t)m * N + col] = (__bf16)v;
      }
    }
  }
}

// ---- chunked affine scan: h_t = f*z + (1-f)*h == a*h + b, a=1-f, b=f*z ----
// pass1: per-chunk composition (A,B): h_out = A*h_in + B
__global__ __launch_bounds__(256) void scan_pass1(const __bf16* __restrict__ Y,
                                                  float* __restrict__ Ac,
                                                  float* __restrict__ Bc) {
  int tid = blockIdx.x * 256 + threadIdx.x;  // 0 .. NCH*BH-1
  int c = tid >> 14;
  int bh = tid & (BH - 1);
  int b = bh >> 10, h = bh & (Hd - 1);
  const size_t sstep = (size_t)Bsz * N;
  size_t base0 = (size_t)b * N + h + (size_t)(c * CS) * sstep;
  float A = 1.0f, B = 0.0f;
  for (int j0 = 0; j0 < CS; j0 += 8) {
    float z[8], f[8];
#pragma unroll
    for (int j = 0; j < 8; ++j) {
      size_t base = base0 + (size_t)(j0 + j) * sstep;
      z[j] = (float)Y[base];
      f[j] = (float)Y[base + Hd];
    }
#pragma unroll
    for (int j = 0; j < 8; ++j) {
      float a = 1.0f - f[j];
      B = fmaf(a, B, f[j] * z[j]);
      A *= a;
    }
  }
  Ac[tid] = A;
  Bc[tid] = B;
}

// pass2: chain chunk states; emit per-chunk h_in and C_last
__global__ __launch_bounds__(256) void scan_pass2(const float* __restrict__ Ac,
                                                  const float* __restrict__ Bc,
                                                  float* __restrict__ hin,
                                                  float* __restrict__ clast) {
  int bh = blockIdx.x * 256 + threadIdx.x;  // 0..BH-1
  float h = 0.0f;
#pragma unroll 4
  for (int c = 0; c < NCH; ++c) {
    hin[c * BH + bh] = h;
    h = fmaf(Ac[c * BH + bh], h, Bc[c * BH + bh]);
  }
  clast[bh] = h;
}

// pass3: replay chunk from known h_in, write Hout = o * h
__global__ __launch_bounds__(256) void scan_pass3(const __bf16* __restrict__ Y,
                                                  const float* __restrict__ hin,
                                                  float* __restrict__ hout) {
  int tid = blockIdx.x * 256 + threadIdx.x;
  int c = tid >> 14;
  int bh = tid & (BH - 1);
  int b = bh >> 10, h = bh & (Hd - 1);
  const size_t sstep = (size_t)Bsz * N;
  size_t base0 = (size_t)b * N + h + (size_t)(c * CS) * sstep;
  size_t obase = (size_t)b * Hd + h + (size_t)(c * CS) * BH;
  float hp = hin[tid];
  for (int j0 = 0; j0 < CS; j0 += 8) {
    float z[8], f[8], o[8];
#pragma unroll
    for (int j = 0; j < 8; ++j) {
      size_t base = base0 + (size_t)(j0 + j) * sstep;
      z[j] = (float)Y[base];
      f[j] = (float)Y[base + Hd];
      o[j] = (float)Y[base + 2 * Hd];
    }
#pragma unroll
    for (int j = 0; j < 8; ++j) {
      hp = fmaf(f[j], z[j] - hp, hp);  // f*z + (1-f)*h
      hout[obase + (size_t)(j0 + j) * BH] = o[j] * hp;
    }
  }
}

extern "C" void kernel_launch(void* const* d_in, const int* in_sizes, int n_in,
                              void* d_out, int out_size, void* d_ws, size_t ws_size,
                              hipStream_t stream) {
  const float* X = (const float*)d_in[0];    // [1024,16,1024]
  const float* W = (const float*)d_in[1];    // [3072,1024]
  const float* bias = (const float*)d_in[2]; // [3072]
  float* out = (float*)d_out;                // Hout (16777216) + C_last (16384)

  char* ws = (char*)d_ws;
  __bf16* Xb = (__bf16*)ws;                      // 33,554,432 B
  __bf16* Wb = (__bf16*)(ws + 33554432);         // 6,291,456 B
  __bf16* Yv = (__bf16*)(ws + 39845888);         // 100,663,296 B (bf16 Y)
  float* Ac = (float*)(ws + 39845888 + 100663296);
  float* Bc = Ac + NCH * BH;                     // 2 MB each
  float* hin = Bc + NCH * BH;

  convert_f32_bf16<<<8192, 256, 0, stream>>>(X, Xb, 2097152);
  convert_f32_bf16<<<1536, 256, 0, stream>>>(W, Wb, 393216);

  dim3 ggrid((M / BM) * (N / BN));  // 3072
  dim3 sgrid(NCH * BH / 256);       // 2048
  gemm_act<<<ggrid, 256, 0, stream>>>(Xb, Wb, bias, Yv);
  scan_pass1<<<sgrid, 256, 0, stream>>>(Yv, Ac, Bc);
  scan_pass2<<<BH / 256, 256, 0, stream>>>(Ac, Bc, hin, out + 16777216);
  scan_pass3<<<sgrid, 256, 0, stream>>>(Yv, hin, out);
}